// Round 1
// baseline (786.346 us; speedup 1.0000x reference)
//
#include <hip/hip_runtime.h>

#define BB 4
#define C 128
#define HH 128
#define WW 128
#define HW 16384
#define K 8
#define O 384

// ---------------- Kernel 1: qkv = w_qkv @ x, output transposed to (B,HW,C) ----
// q -> d_out (scratch reuse), k,v -> ws. Block: 256 thr, 64-pixel tile.
__global__ __launch_bounds__(256) void k_qkv(const float* __restrict__ x,
                                             const float* __restrict__ w_qkv,
                                             float* __restrict__ q_t,
                                             float* __restrict__ k_t,
                                             float* __restrict__ v_t) {
  __shared__ float Xs[C * 64];
  const int b = blockIdx.y;
  const int pix0 = blockIdx.x * 64;
  const int t = threadIdx.x;
  const float* xb = x + (size_t)b * C * HW + pix0;
  #pragma unroll
  for (int i = 0; i < 32; ++i) {
    int linear = i * 256 + t;
    int c = linear >> 6, p = linear & 63;
    Xs[c * 64 + p] = xb[(size_t)c * HW + p];   // coalesced read, conflict-free write
  }
  __syncthreads();
  const int wave = t >> 6, lane = t & 63;
  const size_t outpix = (size_t)b * HW + pix0 + lane;
  for (int i = 0; i < 12; ++i) {
    const int o_base = (wave + 4 * i) * 8;     // 48 chunks of 8 outputs
    float acc[8] = {0, 0, 0, 0, 0, 0, 0, 0};
    const float* wr = w_qkv + (size_t)o_base * C;
    for (int c = 0; c < C; c += 4) {
      float xv0 = Xs[(c + 0) * 64 + lane];
      float xv1 = Xs[(c + 1) * 64 + lane];
      float xv2 = Xs[(c + 2) * 64 + lane];
      float xv3 = Xs[(c + 3) * 64 + lane];
      #pragma unroll
      for (int j = 0; j < 8; ++j) {
        const float4 w4 = *(const float4*)(wr + j * C + c);  // wave-uniform broadcast
        acc[j] += w4.x * xv0 + w4.y * xv1 + w4.z * xv2 + w4.w * xv3;
      }
    }
    float* dst;
    if (o_base < 128)      dst = q_t + outpix * C + o_base;
    else if (o_base < 256) dst = k_t + outpix * C + (o_base - 128);
    else                   dst = v_t + outpix * C + (o_base - 256);
    *(float4*)(dst)     = make_float4(acc[0], acc[1], acc[2], acc[3]);
    *(float4*)(dst + 4) = make_float4(acc[4], acc[5], acc[6], acc[7]);
  }
}

// ---------------- Kernel 2: fused bilinear gather + attention + softmax -------
// One wave per pixel; lane owns 2 channels (float2). psf anchors are ints and
// delta is per-k only => fractional weights/corner offsets are per-k constants.
__global__ __launch_bounds__(256) void k_attn(const float* __restrict__ q_t,
                                              const float* __restrict__ k_t,
                                              const float* __restrict__ v_t,
                                              const int* __restrict__ psf,
                                              const float* __restrict__ delta,
                                              float* __restrict__ ao) {
  const int t = threadIdx.x;
  const int wave = t >> 6, lane = t & 63;
  const int pix = blockIdx.x * 4 + wave;      // 0..65535
  const int b = pix >> 14;

  const float* qp = q_t + (size_t)pix * C + 2 * lane;
  const float qx = qp[0], qy = qp[1];

  float wgt[K][4];
  int dx0[K], dy0[K];
  #pragma unroll
  for (int k = 0; k < K; ++k) {
    float s0 = tanhf(delta[k * 2 + 0]) * 4.0f;  // col shift (grid[...,0] -> x)
    float s1 = tanhf(delta[k * 2 + 1]) * 4.0f;  // row shift
    float f0 = floorf(s0), f1 = floorf(s1);
    dx0[k] = (int)f0; dy0[k] = (int)f1;
    float fx = s0 - f0, fy = s1 - f1;
    wgt[k][0] = (1.0f - fx) * (1.0f - fy);  // (x0,y0)
    wgt[k][1] = fx * (1.0f - fy);           // (x1,y0)
    wgt[k][2] = (1.0f - fx) * fy;           // (x0,y1)
    wgt[k][3] = fx * fy;                    // (x1,y1)
  }

  const int* pp = psf + (size_t)pix * K * 2;
  const float* kb = k_t + (size_t)b * HW * C;
  const float* vb = v_t + (size_t)b * HW * C;

  float logits[K];
  float2 vs[K];
  #pragma unroll
  for (int k = 0; k < K; ++k) {
    const int a0 = pp[k * 2 + 0];   // col anchor
    const int a1 = pp[k * 2 + 1];   // row anchor
    const int x0 = a0 + dx0[k], x1 = x0 + 1;
    const int y0 = a1 + dy0[k], y1 = y0 + 1;
    float ksx = 0, ksy = 0, vsx = 0, vsy = 0;
    #pragma unroll
    for (int cn = 0; cn < 4; ++cn) {
      const int xi = (cn & 1) ? x1 : x0;
      const int yi = (cn & 2) ? y1 : y0;
      const bool valid = (xi >= 0) & (xi <= WW - 1) & (yi >= 0) & (yi <= HH - 1);
      const float wv = valid ? wgt[k][cn] : 0.0f;
      const int xc = min(max(xi, 0), WW - 1);
      const int yc = min(max(yi, 0), HH - 1);
      const size_t idx = ((size_t)(yc * WW + xc)) * C + 2 * lane;
      const float2 kk = *(const float2*)(kb + idx);   // 512B/wave coalesced
      const float2 vv = *(const float2*)(vb + idx);
      ksx += wv * kk.x; ksy += wv * kk.y;
      vsx += wv * vv.x; vsy += wv * vv.y;
    }
    vs[k] = make_float2(vsx, vsy);
    float d = qx * ksx + qy * ksy;
    #pragma unroll
    for (int off = 32; off > 0; off >>= 1) d += __shfl_xor(d, off);
    logits[k] = d * 0.08838834764831845f;   // C^-0.5
  }

  float m = logits[0];
  #pragma unroll
  for (int k = 1; k < K; ++k) m = fmaxf(m, logits[k]);
  float e[K], den = 0.0f;
  #pragma unroll
  for (int k = 0; k < K; ++k) { e[k] = expf(logits[k] - m); den += e[k]; }
  const float inv = 1.0f / den;
  float ox = 0, oy = 0;
  #pragma unroll
  for (int k = 0; k < K; ++k) { float p = e[k] * inv; ox += p * vs[k].x; oy += p * vs[k].y; }
  *(float2*)(ao + (size_t)pix * C + 2 * lane) = make_float2(ox, oy);
}

// ---------------- Kernel 3: out = x + w_proj @ attn_out ----------------------
__global__ __launch_bounds__(256) void k_proj(const float* __restrict__ ao,
                                              const float* __restrict__ w_proj,
                                              const float* __restrict__ x,
                                              float* __restrict__ out) {
  __shared__ float As[C * 65];               // +1 pad: conflict-free transpose
  const int b = blockIdx.y;
  const int pix0 = blockIdx.x * 64;
  const int t = threadIdx.x;
  const float* ab = ao + ((size_t)b * HW + pix0) * C;
  #pragma unroll
  for (int i = 0; i < 32; ++i) {
    int linear = i * 256 + t;
    int c = linear & 127, p = linear >> 7;
    As[c * 65 + p] = ab[p * C + c];          // coalesced read, conflict-free write
  }
  __syncthreads();
  const int wave = t >> 6, lane = t & 63;
  const size_t xoff = (size_t)b * C * HW + pix0 + lane;
  for (int i = 0; i < 4; ++i) {
    const int o_base = (wave * 4 + i) * 8;
    float acc[8] = {0, 0, 0, 0, 0, 0, 0, 0};
    const float* wr = w_proj + (size_t)o_base * C;
    for (int c = 0; c < C; c += 4) {
      float a0 = As[(c + 0) * 65 + lane];
      float a1 = As[(c + 1) * 65 + lane];
      float a2 = As[(c + 2) * 65 + lane];
      float a3 = As[(c + 3) * 65 + lane];
      #pragma unroll
      for (int j = 0; j < 8; ++j) {
        const float4 w4 = *(const float4*)(wr + j * C + c);
        acc[j] += w4.x * a0 + w4.y * a1 + w4.z * a2 + w4.w * a3;
      }
    }
    #pragma unroll
    for (int j = 0; j < 8; ++j) {
      const size_t gi = xoff + (size_t)(o_base + j) * HW;
      out[gi] = x[gi] + acc[j];              // coalesced
    }
  }
}

extern "C" void kernel_launch(void* const* d_in, const int* in_sizes, int n_in,
                              void* d_out, int out_size, void* d_ws, size_t ws_size,
                              hipStream_t stream) {
  const float* x      = (const float*)d_in[0];
  const int*   psf    = (const int*)d_in[1];
  const float* delta  = (const float*)d_in[2];
  const float* w_qkv  = (const float*)d_in[3];
  const float* w_proj = (const float*)d_in[4];
  float* out = (float*)d_out;

  const size_t N = (size_t)BB * HW * C;   // 8388608 floats = 32MB
  float* q_t = out;                        // reuse d_out as q scratch (exactly N)
  float* k_t = (float*)d_ws;
  float* v_t = k_t + N;
  float* ao  = v_t + N;                    // ws need: 96MB

  k_qkv<<<dim3(HW / 64, BB), 256, 0, stream>>>(x, w_qkv, q_t, k_t, v_t);
  k_attn<<<dim3(HW * BB / 4), 256, 0, stream>>>(q_t, k_t, v_t, psf, delta, ao);
  k_proj<<<dim3(HW / 64, BB), 256, 0, stream>>>(ao, w_proj, x, out);
}